// Round 1
// baseline (712.798 us; speedup 1.0000x reference)
//
#include <hip/hip_runtime.h>
#include <math.h>

#define BATCH 64
#define NN 512
#define MM 512
#define DD 128
#define BIGF 1e30f

// ---------------------------------------------------------------------------
// Kernel 1: squared row norms of X (B*N rows) and Y (B*M rows).
// One wave (64 lanes) per row; each lane loads 2 floats; shuffle reduce.
// ---------------------------------------------------------------------------
__global__ __launch_bounds__(256) void sqnorm_kernel(const float* __restrict__ X,
                                                     const float* __restrict__ Y,
                                                     float* __restrict__ x2,
                                                     float* __restrict__ y2) {
    int row  = blockIdx.x * 4 + (threadIdx.x >> 6);
    int lane = threadIdx.x & 63;
    const float* src;
    float* dst;
    int r;
    if (row < BATCH * NN) { src = X; dst = x2; r = row; }
    else                  { src = Y; dst = y2; r = row - BATCH * NN; }
    const float* p = src + (size_t)r * DD;
    float a = p[lane];
    float b = p[lane + 64];
    float s = a * a + b * b;
    #pragma unroll
    for (int m = 32; m >= 1; m >>= 1) s += __shfl_xor(s, m, 64);
    if (lane == 0) dst[r] = s;
}

// ---------------------------------------------------------------------------
// Kernel 2: C[b,i,j] = (x2[b,i] + y2[b,j] - 2*dot(X[b,i,:], Y[b,j,:])) / D
// Tiled fp32 GEMM: 64x64 tile per 256-thread block, 4x4 micro-tile/thread.
// LDS pad = 136 floats keeps Y-tile b128 reads at <=4-way bank conflict.
// ---------------------------------------------------------------------------
#define TM 64
#define LDP 136

__global__ __launch_bounds__(256) void cost_kernel(const float* __restrict__ X,
                                                   const float* __restrict__ Y,
                                                   const float* __restrict__ x2,
                                                   const float* __restrict__ y2,
                                                   float* __restrict__ C) {
    __shared__ float Xs[TM][LDP];
    __shared__ float Ys[TM][LDP];
    int b  = blockIdx.z;
    int ti = blockIdx.y * TM;
    int tj = blockIdx.x * TM;
    int t  = threadIdx.x;
    const float* Xb = X + ((size_t)b * NN + ti) * DD;
    const float* Yb = Y + ((size_t)b * MM + tj) * DD;

    int r0 = t >> 5;          // 0..7
    int c4 = (t & 31) * 4;    // 0..124, step 4
    #pragma unroll
    for (int it = 0; it < 8; ++it) {
        int r = r0 + it * 8;
        *(float4*)&Xs[r][c4] = *(const float4*)&Xb[(size_t)r * DD + c4];
        *(float4*)&Ys[r][c4] = *(const float4*)&Yb[(size_t)r * DD + c4];
    }
    __syncthreads();

    int tx = t & 15, ty = t >> 4;
    float acc[4][4] = {};
    #pragma unroll 2
    for (int k = 0; k < DD; k += 4) {
        float4 xa[4], yb[4];
        #pragma unroll
        for (int m = 0; m < 4; ++m) xa[m] = *(const float4*)&Xs[ty * 4 + m][k];
        #pragma unroll
        for (int n2 = 0; n2 < 4; ++n2) yb[n2] = *(const float4*)&Ys[tx * 4 + n2][k];
        #pragma unroll
        for (int m = 0; m < 4; ++m)
            #pragma unroll
            for (int n2 = 0; n2 < 4; ++n2)
                acc[m][n2] += xa[m].x * yb[n2].x + xa[m].y * yb[n2].y
                            + xa[m].z * yb[n2].z + xa[m].w * yb[n2].w;
    }

    const float inv = 1.0f / (float)DD;
    #pragma unroll
    for (int m = 0; m < 4; ++m) {
        int i = ti + ty * 4 + m;
        float xx = x2[b * NN + i];
        int j = tj + tx * 4;
        float4 o;
        o.x = (xx + y2[b * MM + j + 0] - 2.0f * acc[m][0]) * inv;
        o.y = (xx + y2[b * MM + j + 1] - 2.0f * acc[m][1]) * inv;
        o.z = (xx + y2[b * MM + j + 2] - 2.0f * acc[m][2]) * inv;
        o.w = (xx + y2[b * MM + j + 3] - 2.0f * acc[m][3]) * inv;
        *(float4*)&C[((size_t)b * NN + i) * MM + j] = o;
    }
}

// ---------------------------------------------------------------------------
// Kernel 3: soft-DTW over anti-diagonals. One 512-thread block per batch.
// Thread i owns row i. 3 rotating LDS diagonal buffers; own previous value
// kept in a register (only the i-1 neighbor goes through LDS).
// R[d][i] = C[i][d-i] + softmin(R[d-1][i-1], R[d-1][i], R[d-2][i-1])
// ---------------------------------------------------------------------------
__global__ __launch_bounds__(512) void sdtw_kernel(const float* __restrict__ C,
                                                   float* __restrict__ part) {
    __shared__ float buf[3][NN];
    int b = blockIdx.x;
    int i = threadIdx.x;
    const float* Cb = C + ((size_t)b * NN + i) * MM;

    buf[0][i] = BIGF;   // R[d-1]
    buf[1][i] = BIGF;   // R[d-2]
    float rp = BIGF;    // own R[d-1][i]
    int pa = 0, pb = 1, pc = 2;
    __syncthreads();

    float c_cur = (i == 0) ? Cb[0] : 0.0f;  // d=0: j=-i valid only at i=0
    for (int d = 0; d < NN + MM - 1; ++d) {
        // prefetch next diagonal's cost
        int jn = d + 1 - i;
        float c_next = (jn >= 0 && jn < MM) ? Cb[jn] : 0.0f;

        float left = (i > 0) ? buf[pa][i - 1] : BIGF;  // R[d-1][i-1]
        float diag = (i > 0) ? buf[pb][i - 1] : BIGF;  // R[d-2][i-1]
        float c  = c_cur;
        float a0 = left + c;
        float a1 = rp   + c;
        float a2 = diag + c;
        float mn = fminf(a0, fminf(a1, a2));
        float s  = __expf(mn - a0) + __expf(mn - a1) + __expf(mn - a2);
        float r  = mn - __logf(s);            // GAMMA = 1
        if (d == 0 && i == 0) r = c;
        int j = d - i;
        if (j < 0 || j >= MM) r = BIGF;

        buf[pc][i] = r;
        rp = r;
        __syncthreads();
        int tmp = pb; pb = pa; pa = pc; pc = tmp;
        c_cur = c_next;
    }
    if (i == NN - 1) part[b] = rp;   // R[N-1][M-1]
}

// ---------------------------------------------------------------------------
// Kernel 4: deterministic reduction of 64 per-batch results.
// out = sum_b(R_b) / (B * N)
// ---------------------------------------------------------------------------
__global__ void reduce_kernel(const float* __restrict__ part, float* __restrict__ out) {
    if (threadIdx.x == 0) {
        float s = 0.0f;
        for (int b2 = 0; b2 < BATCH; ++b2) s += part[b2];
        out[0] = s / (float)(BATCH * NN);
    }
}

// ---------------------------------------------------------------------------
extern "C" void kernel_launch(void* const* d_in, const int* in_sizes, int n_in,
                              void* d_out, int out_size, void* d_ws, size_t ws_size,
                              hipStream_t stream) {
    const float* X = (const float*)d_in[0];
    const float* Y = (const float*)d_in[1];
    float* out = (float*)d_out;

    char* ws = (char*)d_ws;
    float* C    = (float*)ws;                                   // 64 MB
    float* x2   = (float*)(ws + (size_t)BATCH * NN * MM * 4);   // 128 KB
    float* y2   = x2 + BATCH * NN;                              // 128 KB
    float* part = y2 + BATCH * MM;                              // 256 B

    sqnorm_kernel<<<(BATCH * (NN + MM)) / 4, 256, 0, stream>>>(X, Y, x2, y2);

    dim3 g(MM / TM, NN / TM, BATCH);
    cost_kernel<<<g, 256, 0, stream>>>(X, Y, x2, y2, C);

    sdtw_kernel<<<BATCH, NN, 0, stream>>>(C, part);

    reduce_kernel<<<1, 64, 0, stream>>>(part, out);
}

// Round 2
// 437.554 us; speedup vs baseline: 1.6291x; 1.6291x over previous
//
#include <hip/hip_runtime.h>
#include <math.h>

#define BATCH 64
#define NN 512
#define MM 512
#define DD 128
#define BIGF 1e30f

// ---------------------------------------------------------------------------
// Kernel 1: squared row norms of X (B*N rows) and Y (B*M rows).
// One wave (64 lanes) per row; each lane loads 2 floats; shuffle reduce.
// ---------------------------------------------------------------------------
__global__ __launch_bounds__(256) void sqnorm_kernel(const float* __restrict__ X,
                                                     const float* __restrict__ Y,
                                                     float* __restrict__ x2,
                                                     float* __restrict__ y2) {
    int row  = blockIdx.x * 4 + (threadIdx.x >> 6);
    int lane = threadIdx.x & 63;
    const float* src;
    float* dst;
    int r;
    if (row < BATCH * NN) { src = X; dst = x2; r = row; }
    else                  { src = Y; dst = y2; r = row - BATCH * NN; }
    const float* p = src + (size_t)r * DD;
    float a = p[lane];
    float b = p[lane + 64];
    float s = a * a + b * b;
    #pragma unroll
    for (int m = 32; m >= 1; m >>= 1) s += __shfl_xor(s, m, 64);
    if (lane == 0) dst[r] = s;
}

// ---------------------------------------------------------------------------
// Kernel 2: CT[b,j,i] = (x2[b,i] + y2[b,j] - 2*dot(X[b,i,:], Y[b,j,:])) / D
// (TRANSPOSED output so the DTW kernel reads contiguous i-runs per column.)
// 64x64 tile per 256-thread block, 4x4 micro-tile. LDS stored linearly with a
// float4 XOR swizzle (slot = row*32 + (k4 ^ ((row>>2)&7))):
//   - staging writes: contiguous per half-wave -> conflict-free
//   - xa reads (rows 4*tx+m): 2 lanes/bank -> free (m136)
//   - yb reads (rows 4*ty+n): 4 broadcast addrs, distinct banks -> free
// tx (fastest lane index) maps to i so the CT write is 256B-contiguous.
// ---------------------------------------------------------------------------
#define TM 64

__global__ __launch_bounds__(256) void cost_kernel(const float* __restrict__ X,
                                                   const float* __restrict__ Y,
                                                   const float* __restrict__ x2,
                                                   const float* __restrict__ y2,
                                                   float* __restrict__ CT) {
    __shared__ float Xs[TM * DD];
    __shared__ float Ys[TM * DD];
    int b  = blockIdx.z;
    int ti = blockIdx.y * TM;
    int tj = blockIdx.x * TM;
    int t  = threadIdx.x;
    const float* Xb = X + ((size_t)b * NN + ti) * DD;
    const float* Yb = Y + ((size_t)b * MM + tj) * DD;

    int k4l = t & 31;          // float4 col 0..31
    int rl  = t >> 5;          // 0..7
    #pragma unroll
    for (int it = 0; it < 8; ++it) {
        int r  = rl + it * 8;
        int sw = r * 32 + (k4l ^ ((r >> 2) & 7));
        *(float4*)&Xs[4 * sw] = *(const float4*)&Xb[(size_t)r * DD + 4 * k4l];
        *(float4*)&Ys[4 * sw] = *(const float4*)&Yb[(size_t)r * DD + 4 * k4l];
    }
    __syncthreads();

    int tx = t & 15;   // i micro index (fastest -> coalesced CT store)
    int ty = t >> 4;   // j micro index
    float acc[4][4] = {};   // [m over i][n over j]
    #pragma unroll 4
    for (int k4 = 0; k4 < 32; ++k4) {
        float4 xa[4], yb[4];
        int kx = k4 ^ (tx & 7);
        int ky = k4 ^ ty;       // ty < 4
        #pragma unroll
        for (int m = 0; m < 4; ++m)
            xa[m] = *(const float4*)&Xs[4 * ((tx * 4 + m) * 32 + kx)];
        #pragma unroll
        for (int n = 0; n < 4; ++n)
            yb[n] = *(const float4*)&Ys[4 * ((ty * 4 + n) * 32 + ky)];
        #pragma unroll
        for (int m = 0; m < 4; ++m)
            #pragma unroll
            for (int n = 0; n < 4; ++n)
                acc[m][n] += xa[m].x * yb[n].x + xa[m].y * yb[n].y
                           + xa[m].z * yb[n].z + xa[m].w * yb[n].w;
    }

    const float inv = 1.0f / (float)DD;
    int i0 = ti + tx * 4;
    float4 xx = *(const float4*)&x2[b * NN + i0];
    #pragma unroll
    for (int n = 0; n < 4; ++n) {
        int j = tj + ty * 4 + n;
        float yy = y2[b * MM + j];
        float4 o;
        o.x = (xx.x + yy - 2.0f * acc[0][n]) * inv;
        o.y = (xx.y + yy - 2.0f * acc[1][n]) * inv;
        o.z = (xx.z + yy - 2.0f * acc[2][n]) * inv;
        o.w = (xx.w + yy - 2.0f * acc[3][n]) * inv;
        *(float4*)&CT[((size_t)b * MM + j) * NN + i0] = o;
    }
}

// ---------------------------------------------------------------------------
// Kernel 3: wave-synchronous soft-DTW. One 64-lane wave per batch; lane t owns
// rows [8t, 8t+8) held in registers. Lane t computes its 8 cells of column
// j = s - t at super-step s (575 steps). The only cross-lane value is the
// lane's bottom-row cell, passed by __shfl_up each step: nb_cur = neighbor
// bottom at column j, nb_prev = at column j-1. No LDS, no barriers.
// Cell: v = c + [minx - log(sum exp(minx - x_i))], x = {up, left, updiag}.
// BIG boundaries absorb exactly as in the reference (exp(-1e30)=0, BIG+f=BIG).
// ---------------------------------------------------------------------------
__global__ __launch_bounds__(64) void sdtw_kernel(const float* __restrict__ CT,
                                                  float* __restrict__ part) {
    int b = blockIdx.x;
    int t = threadIdx.x;           // 0..63
    const float* Cb = CT + (size_t)b * MM * NN;   // CT[j][i]
    int r0 = t * 8;

    float prev[8];                 // own column j-1 values
    #pragma unroll
    for (int r = 0; r < 8; ++r) prev[r] = BIGF;
    float nb_cur = BIGF, nb_prev = BIGF;

    float4 pA = {BIGF,BIGF,BIGF,BIGF}, pB = {BIGF,BIGF,BIGF,BIGF};
    if (t == 0) {                  // prefetch column 0 (only lane 0 active at s=0)
        pA = *(const float4*)&Cb[r0];
        pB = *(const float4*)&Cb[r0 + 4];
    }

    for (int s = 0; s < MM + 63; ++s) {
        int j = s - t;
        float4 cA = pA, cB = pB;
        int j2 = j + 1;
        if (j2 >= 0 && j2 < MM) {  // prefetch next column (1 step ~ 350 cyc ahead)
            pA = *(const float4*)&Cb[(size_t)j2 * NN + r0];
            pB = *(const float4*)&Cb[(size_t)j2 * NN + r0 + 4];
        }
        if (j >= 0 && j < MM) {
            float cc[8] = {cA.x, cA.y, cA.z, cA.w, cB.x, cB.y, cB.z, cB.w};
            float up = (t == 0) ? BIGF : nb_cur;   // (r0-1, j)
            float ud = (t == 0) ? BIGF : nb_prev;  // (r0-1, j-1)
            #pragma unroll
            for (int r = 0; r < 8; ++r) {
                float left = prev[r];              // (r0+r, j-1)
                float mn = fminf(up, fminf(left, ud));
                float sum = __expf(mn - up) + __expf(mn - left) + __expf(mn - ud);
                float v = cc[r] + (mn - __logf(sum));
                if (r == 0 && t == 0 && j == 0) v = cc[0];   // cell (0,0)
                prev[r] = v;
                ud = left;                         // (r-1, j-1) for next r
                up = v;                            // (r-1, j)   for next r
            }
        }
        float sh = __shfl_up(prev[7], 1);          // my bottom -> lane t+1
        nb_prev = nb_cur;
        nb_cur = sh;
    }
    if (t == 63) part[b] = prev[7];                // cell (511, 511)
}

// ---------------------------------------------------------------------------
// Kernel 4: deterministic reduction. out = sum_b(R_b) / (B * N)
// ---------------------------------------------------------------------------
__global__ void reduce_kernel(const float* __restrict__ part, float* __restrict__ out) {
    if (threadIdx.x == 0) {
        float s = 0.0f;
        for (int b2 = 0; b2 < BATCH; ++b2) s += part[b2];
        out[0] = s / (float)(BATCH * NN);
    }
}

// ---------------------------------------------------------------------------
extern "C" void kernel_launch(void* const* d_in, const int* in_sizes, int n_in,
                              void* d_out, int out_size, void* d_ws, size_t ws_size,
                              hipStream_t stream) {
    const float* X = (const float*)d_in[0];
    const float* Y = (const float*)d_in[1];
    float* out = (float*)d_out;

    char* ws = (char*)d_ws;
    float* CT   = (float*)ws;                                   // 64 MB
    float* x2   = (float*)(ws + (size_t)BATCH * NN * MM * 4);   // 128 KB
    float* y2   = x2 + BATCH * NN;                              // 128 KB
    float* part = y2 + BATCH * MM;                              // 256 B

    sqnorm_kernel<<<(BATCH * (NN + MM)) / 4, 256, 0, stream>>>(X, Y, x2, y2);

    dim3 g(MM / TM, NN / TM, BATCH);
    cost_kernel<<<g, 256, 0, stream>>>(X, Y, x2, y2, CT);

    sdtw_kernel<<<BATCH, 64, 0, stream>>>(CT, part);

    reduce_kernel<<<1, 64, 0, stream>>>(part, out);
}

// Round 3
// 280.649 us; speedup vs baseline: 2.5398x; 1.5591x over previous
//
#include <hip/hip_runtime.h>
#include <math.h>

#define BATCH 64
#define NN 512
#define MM 512
#define DD 128
#define BIGF 1e30f

// ---------------------------------------------------------------------------
// Kernel 1: squared row norms of X (B*N rows) and Y (B*M rows).
// ---------------------------------------------------------------------------
__global__ __launch_bounds__(256) void sqnorm_kernel(const float* __restrict__ X,
                                                     const float* __restrict__ Y,
                                                     float* __restrict__ x2,
                                                     float* __restrict__ y2) {
    int row  = blockIdx.x * 4 + (threadIdx.x >> 6);
    int lane = threadIdx.x & 63;
    const float* src;
    float* dst;
    int r;
    if (row < BATCH * NN) { src = X; dst = x2; r = row; }
    else                  { src = Y; dst = y2; r = row - BATCH * NN; }
    const float* p = src + (size_t)r * DD;
    float a = p[lane];
    float b = p[lane + 64];
    float s = a * a + b * b;
    #pragma unroll
    for (int m = 32; m >= 1; m >>= 1) s += __shfl_xor(s, m, 64);
    if (lane == 0) dst[r] = s;
}

// ---------------------------------------------------------------------------
// Kernel 2: CT[b,j,i] = (x2[b,i] + y2[b,j] - 2*dot(X[b,i,:], Y[b,j,:])) / D
// (transposed output; float4-XOR-swizzled LDS; tx->i so stores coalesce)
// ---------------------------------------------------------------------------
#define TM 64

__global__ __launch_bounds__(256) void cost_kernel(const float* __restrict__ X,
                                                   const float* __restrict__ Y,
                                                   const float* __restrict__ x2,
                                                   const float* __restrict__ y2,
                                                   float* __restrict__ CT) {
    __shared__ float Xs[TM * DD];
    __shared__ float Ys[TM * DD];
    int b  = blockIdx.z;
    int ti = blockIdx.y * TM;
    int tj = blockIdx.x * TM;
    int t  = threadIdx.x;
    const float* Xb = X + ((size_t)b * NN + ti) * DD;
    const float* Yb = Y + ((size_t)b * MM + tj) * DD;

    int k4l = t & 31;
    int rl  = t >> 5;
    #pragma unroll
    for (int it = 0; it < 8; ++it) {
        int r  = rl + it * 8;
        int sw = r * 32 + (k4l ^ ((r >> 2) & 7));
        *(float4*)&Xs[4 * sw] = *(const float4*)&Xb[(size_t)r * DD + 4 * k4l];
        *(float4*)&Ys[4 * sw] = *(const float4*)&Yb[(size_t)r * DD + 4 * k4l];
    }
    __syncthreads();

    int tx = t & 15;
    int ty = t >> 4;
    float acc[4][4] = {};
    #pragma unroll 4
    for (int k4 = 0; k4 < 32; ++k4) {
        float4 xa[4], yb[4];
        int kx = k4 ^ (tx & 7);
        int ky = k4 ^ ty;
        #pragma unroll
        for (int m = 0; m < 4; ++m)
            xa[m] = *(const float4*)&Xs[4 * ((tx * 4 + m) * 32 + kx)];
        #pragma unroll
        for (int n = 0; n < 4; ++n)
            yb[n] = *(const float4*)&Ys[4 * ((ty * 4 + n) * 32 + ky)];
        #pragma unroll
        for (int m = 0; m < 4; ++m)
            #pragma unroll
            for (int n = 0; n < 4; ++n)
                acc[m][n] += xa[m].x * yb[n].x + xa[m].y * yb[n].y
                           + xa[m].z * yb[n].z + xa[m].w * yb[n].w;
    }

    const float inv = 1.0f / (float)DD;
    int i0 = ti + tx * 4;
    float4 xx = *(const float4*)&x2[b * NN + i0];
    #pragma unroll
    for (int n = 0; n < 4; ++n) {
        int j = tj + ty * 4 + n;
        float yy = y2[b * MM + j];
        float4 o;
        o.x = (xx.x + yy - 2.0f * acc[0][n]) * inv;
        o.y = (xx.y + yy - 2.0f * acc[1][n]) * inv;
        o.z = (xx.z + yy - 2.0f * acc[2][n]) * inv;
        o.w = (xx.w + yy - 2.0f * acc[3][n]) * inv;
        *(float4*)&CT[((size_t)b * MM + j) * NN + i0] = o;
    }
}

// ---------------------------------------------------------------------------
// Kernel 3: wave-synchronous soft-DTW, base-2 scaled domain, depth-3 prefetch.
// One wave per batch; lane t owns rows [8t,8t+8) in registers; lane t computes
// column j = s - t at super-step s. Cross-lane: one __shfl_up per step.
// Scaled domain: w = v*log2(e). min is scale-invariant, so
//   w = cK + min3(uw,lw,dw) - log2( 2^(m-uw) + 2^(m-lw) + 2^(m-dw) )
// with raw v_exp_f32/v_log_f32 (base-2 HW ops, no chain-side scaling muls).
// Depth-3 rotating prefetch (p0<-p1<-p2<-load(j+3)) hides ~900cyc HBM latency.
// ---------------------------------------------------------------------------
#define KLOG2E 1.442695040888963f
#define LN2F   0.693147180559945f
#define BIGK   (BIGF * KLOG2E)

__global__ __launch_bounds__(64) void sdtw_kernel(const float* __restrict__ CT,
                                                  float* __restrict__ part) {
    int b = blockIdx.x;
    int t = threadIdx.x;
    const float* Cb = CT + (size_t)b * MM * NN;   // CT[j][i]
    int r0 = t * 8;

    float prev[8];
    #pragma unroll
    for (int r = 0; r < 8; ++r) prev[r] = BIGK;
    float nb_cur = BIGK, nb_prev = BIGK;

    float4 z4 = {0.f, 0.f, 0.f, 0.f};
    float4 p0A = z4, p0B = z4, p1A = z4, p1B = z4, p2A = z4, p2B = z4;
    {   // prologue: columns (0-t), (1-t), (2-t) where valid
        int j = -t;
        if (j >= 0) { p0A = *(const float4*)&Cb[(size_t)j * NN + r0];
                      p0B = *(const float4*)&Cb[(size_t)j * NN + r0 + 4]; }
        j = 1 - t;
        if (j >= 0) { p1A = *(const float4*)&Cb[(size_t)j * NN + r0];
                      p1B = *(const float4*)&Cb[(size_t)j * NN + r0 + 4]; }
        j = 2 - t;
        if (j >= 0) { p2A = *(const float4*)&Cb[(size_t)j * NN + r0];
                      p2B = *(const float4*)&Cb[(size_t)j * NN + r0 + 4]; }
    }

    #pragma unroll 3
    for (int s = 0; s < MM + 63; ++s) {
        int j = s - t;
        float4 cA = p0A, cB = p0B;
        p0A = p1A; p0B = p1B;
        p1A = p2A; p1B = p2B;
        int jn = j + 3;
        if (jn >= 0 && jn < MM) {
            p2A = *(const float4*)&Cb[(size_t)jn * NN + r0];
            p2B = *(const float4*)&Cb[(size_t)jn * NN + r0 + 4];
        }
        if (j >= 0 && j < MM) {
            float cc[8] = {cA.x, cA.y, cA.z, cA.w, cB.x, cB.y, cB.z, cB.w};
            float up = (t == 0) ? BIGK : nb_cur;   // (r0-1, j)
            float ud = (t == 0) ? BIGK : nb_prev;  // (r0-1, j-1)
            #pragma unroll
            for (int r = 0; r < 8; ++r) {
                float left = prev[r];              // (r0+r, j-1)
                float ck = cc[r] * KLOG2E;         // off critical chain
                float mn;
                asm("v_min3_f32 %0, %1, %2, %3" : "=v"(mn) : "v"(up), "v"(left), "v"(ud));
                float e0, e1, e2;
                float d0 = mn - up, d1 = mn - left, d2 = mn - ud;
                asm("v_exp_f32 %0, %1" : "=v"(e0) : "v"(d0));
                asm("v_exp_f32 %0, %1" : "=v"(e1) : "v"(d1));
                asm("v_exp_f32 %0, %1" : "=v"(e2) : "v"(d2));
                float sum = (e0 + e1) + e2;
                float lg;
                asm("v_log_f32 %0, %1" : "=v"(lg) : "v"(sum));
                float v = ck + (mn - lg);
                if (r == 0 && t == 0 && j == 0) v = ck;   // cell (0,0)
                prev[r] = v;
                ud = left;
                up = v;
            }
        }
        float sh = __shfl_up(prev[7], 1);
        nb_prev = nb_cur;
        nb_cur = sh;
    }
    if (t == 63) part[b] = prev[7] * LN2F;   // back to nats: cell (511,511)
}

// ---------------------------------------------------------------------------
// Kernel 4: deterministic reduction. out = sum_b(R_b) / (B * N)
// ---------------------------------------------------------------------------
__global__ void reduce_kernel(const float* __restrict__ part, float* __restrict__ out) {
    if (threadIdx.x == 0) {
        float s = 0.0f;
        for (int b2 = 0; b2 < BATCH; ++b2) s += part[b2];
        out[0] = s / (float)(BATCH * NN);
    }
}

// ---------------------------------------------------------------------------
extern "C" void kernel_launch(void* const* d_in, const int* in_sizes, int n_in,
                              void* d_out, int out_size, void* d_ws, size_t ws_size,
                              hipStream_t stream) {
    const float* X = (const float*)d_in[0];
    const float* Y = (const float*)d_in[1];
    float* out = (float*)d_out;

    char* ws = (char*)d_ws;
    float* CT   = (float*)ws;                                   // 64 MB
    float* x2   = (float*)(ws + (size_t)BATCH * NN * MM * 4);   // 128 KB
    float* y2   = x2 + BATCH * NN;                              // 128 KB
    float* part = y2 + BATCH * MM;                              // 256 B

    sqnorm_kernel<<<(BATCH * (NN + MM)) / 4, 256, 0, stream>>>(X, Y, x2, y2);

    dim3 g(MM / TM, NN / TM, BATCH);
    cost_kernel<<<g, 256, 0, stream>>>(X, Y, x2, y2, CT);

    sdtw_kernel<<<BATCH, 64, 0, stream>>>(CT, part);

    reduce_kernel<<<1, 64, 0, stream>>>(part, out);
}